// Round 1
// baseline (14787.468 us; speedup 1.0000x reference)
//
#include <hip/hip_runtime.h>
#include <cmath>

#define EIDN  30000
#define EMBN  256
#define HIDN  512
#define INDIM 3
#define SRCT  128
#define TRGT  50
#define BN    64
#define G3H   1536   // 3*HIDN

// Workspace layout. If ws_size is too small we fall back to aliasing the
// t=0 output slice (7.68 MB, zeroed at the very end) as scratch.
struct WS {
  float whhT[HIDN * G3H];           // transposed W_hh_enc: [k][j] 512x1536
  float hb[2][BN][HIDN];            // ping-pong hidden state
  float rowsum[BN];                 // sum(exp(logit)) per row
  float rate_cur[BN];
  int   eid_cur[BN];
  unsigned long long amax[BN];      // packed argmax: orderf(val)<<32 | (~col)
};

__device__ __forceinline__ float sigmoidf_(float x) { return 1.f / (1.f + expf(-x)); }

__device__ __forceinline__ unsigned int orderf_(float f) {
  unsigned int b = __float_as_uint(f);
  return b ^ ((b & 0x80000000u) ? 0xFFFFFFFFu : 0x80000000u);
}

__device__ __forceinline__ unsigned long long shfl_down_u64(unsigned long long v, int off, int w) {
  unsigned int lo = (unsigned int)v;
  unsigned int hi = (unsigned int)(v >> 32);
  lo = __shfl_down(lo, off, w);
  hi = __shfl_down(hi, off, w);
  return ((unsigned long long)hi << 32) | (unsigned long long)lo;
}

// ---------------------------------------------------------------- init/prep
__global__ void k_init(const float* __restrict__ Whh_enc,
                       const int* __restrict__ trg_eid,
                       const float* __restrict__ trg_rate,
                       float* __restrict__ out, WS* __restrict__ ws) {
  int tid = blockIdx.x * blockDim.x + threadIdx.x;
  int nt = gridDim.x * blockDim.x;
  // transpose W_hh_enc [1536,512] -> [512,1536] (coalesced writes)
  for (int i = tid; i < HIDN * G3H; i += nt) {
    int k = i / G3H, j = i - k * G3H;
    ws->whhT[i] = Whh_enc[j * HIDN + k];
  }
  if (tid < BN) {
    ws->eid_cur[tid]  = trg_eid[tid];    // trg_eid[0][b]
    ws->rate_cur[tid] = trg_rate[tid];   // trg_rate[0][b]
    out[(size_t)TRGT * BN * EIDN + tid] = 0.f;  // rate_result row 0
  }
}

// ---------------------------------------------------------------- encoder
// one WG per batch element; h in LDS; loop runs only t < src_len[b]
__global__ __launch_bounds__(512) void k_encoder(
    const float* __restrict__ src, const int* __restrict__ src_len,
    const float* __restrict__ Wih, const float* __restrict__ bih,
    const float* __restrict__ bhh, WS* __restrict__ ws) {
  int b = blockIdx.x;
  int j = threadIdx.x;                 // 0..511, one hidden unit per thread
  __shared__ float hs[HIDN];
  hs[j] = 0.f;
  __syncthreads();
  float wi[3][3], bi[3], bh[3];
#pragma unroll
  for (int g = 0; g < 3; ++g) {
#pragma unroll
    for (int k = 0; k < 3; ++k) wi[g][k] = Wih[(g * HIDN + j) * INDIM + k];
    bi[g] = bih[g * HIDN + j];
    bh[g] = bhh[g * HIDN + j];
  }
  int len = src_len[b];
  const float* __restrict__ WT = ws->whhT;
  for (int t = 0; t < len; ++t) {
    const float* x = src + ((size_t)t * BN + b) * INDIM;
    float x0 = x[0], x1 = x[1], x2 = x[2];
    float gr = bi[0] + wi[0][0]*x0 + wi[0][1]*x1 + wi[0][2]*x2;
    float gz = bi[1] + wi[1][0]*x0 + wi[1][1]*x1 + wi[1][2]*x2;
    float gn = bi[2] + wi[2][0]*x0 + wi[2][1]*x1 + wi[2][2]*x2;
    float hr = bh[0], hz = bh[1], hn = bh[2];
#pragma unroll 4
    for (int k = 0; k < HIDN; ++k) {
      float hk = hs[k];
      const float* w = WT + k * G3H + j;   // lanes j: coalesced
      hr = fmaf(hk, w[0],        hr);
      hz = fmaf(hk, w[HIDN],     hz);
      hn = fmaf(hk, w[2 * HIDN], hn);
    }
    float r = sigmoidf_(gr + hr);
    float z = sigmoidf_(gz + hz);
    float n = tanhf(gn + r * hn);
    float hnew = (1.f - z) * n + z * hs[j];
    __syncthreads();
    hs[j] = hnew;
    __syncthreads();
  }
  ws->hb[0][b][j] = hs[j];
}

// ---------------------------------------------------------------- decoder GRU cell
// grid 128: each WG owns 4 hidden units j for all 64 batch rows.
__global__ __launch_bounds__(256) void k_dec_gru(
    const float* __restrict__ emb_dec, const float* __restrict__ Wih,
    const float* __restrict__ Whh, const float* __restrict__ bih,
    const float* __restrict__ bhh, WS* __restrict__ ws,
    const float* __restrict__ hin, float* __restrict__ hout) {
  int tid = threadIdx.x;
  if (blockIdx.x == 0 && tid < BN) {   // reset reductions for upcoming k_logits
    ws->rowsum[tid] = 0.f;
    ws->amax[tid] = 0ULL;
  }
  int jj = tid & 3;
  int b = tid >> 2;
  int j = blockIdx.x * 4 + jj;
  int eid = ws->eid_cur[b];
  float rate = ws->rate_cur[b];
  const float* xe = emb_dec + (size_t)eid * EMBN;
  const float* h = hin + b * HIDN;
  float g0 = bih[j], g1 = bih[HIDN + j], g2 = bih[2 * HIDN + j];
  const float* wr0 = Wih + (size_t)j * (EMBN + 1);
  const float* wr1 = Wih + (size_t)(HIDN + j) * (EMBN + 1);
  const float* wr2 = Wih + (size_t)(2 * HIDN + j) * (EMBN + 1);
#pragma unroll 4
  for (int k = 0; k < EMBN; ++k) {
    float xk = xe[k];
    g0 = fmaf(xk, wr0[k], g0);
    g1 = fmaf(xk, wr1[k], g1);
    g2 = fmaf(xk, wr2[k], g2);
  }
  g0 = fmaf(rate, wr0[EMBN], g0);
  g1 = fmaf(rate, wr1[EMBN], g1);
  g2 = fmaf(rate, wr2[EMBN], g2);
  float h0 = bhh[j], h1 = bhh[HIDN + j], h2 = bhh[2 * HIDN + j];
  const float* vr0 = Whh + (size_t)j * HIDN;
  const float* vr1 = Whh + (size_t)(HIDN + j) * HIDN;
  const float* vr2 = Whh + (size_t)(2 * HIDN + j) * HIDN;
#pragma unroll 4
  for (int k = 0; k < HIDN; ++k) {
    float hk = h[k];
    h0 = fmaf(hk, vr0[k], h0);
    h1 = fmaf(hk, vr1[k], h1);
    h2 = fmaf(hk, vr2[k], h2);
  }
  float r = sigmoidf_(g0 + h0);
  float z = sigmoidf_(g1 + h1);
  float n = tanhf(g2 + r * h2);
  hout[b * HIDN + j] = (1.f - z) * n + z * h[j];
}

// ---------------------------------------------------------------- big GEMM + reductions
// grid 235: WG owns 128 columns of W_eid for all 64 rows. LDS-tiled fp32 GEMM.
// Writes RAW logits into the output slice (normalized in-place by k_finalize),
// accumulates rowsum=sum(exp(l)) and packed argmax via atomics.
__global__ __launch_bounds__(256) void k_logits(
    const float* __restrict__ Weid, const float* __restrict__ beid,
    const float* __restrict__ h, float* __restrict__ oslice,
    WS* __restrict__ ws) {
  __shared__ float sw[64][132];   // W tile [k][c], padded
  __shared__ float sh[64][68];    // h tile [k][r], padded
  int tid = threadIdx.x;
  int tr = tid >> 4, tc = tid & 15;   // 16x16 thread grid; cells 4r x 8c (c strided 16)
  int c0 = blockIdx.x * 128;
  float acc[4][8];
#pragma unroll
  for (int i = 0; i < 4; ++i)
#pragma unroll
    for (int m = 0; m < 8; ++m) acc[i][m] = 0.f;

  for (int kc = 0; kc < 8; ++kc) {
    int k0 = kc * 64;
    // stage h chunk [64r][64k]
#pragma unroll
    for (int u = 0; u < 4; ++u) {
      int flat = tid + u * 256;
      int r = flat >> 4, kf = flat & 15;
      const float4 hv = *(const float4*)(h + r * HIDN + k0 + kf * 4);
      sh[kf * 4 + 0][r] = hv.x; sh[kf * 4 + 1][r] = hv.y;
      sh[kf * 4 + 2][r] = hv.z; sh[kf * 4 + 3][r] = hv.w;
    }
    // stage W tile [128c][64k] (transposed into [k][c])
    {
      int k4 = tid >> 4;   // 0..15 -> k quad
      int cl = tid & 15;
#pragma unroll
      for (int it = 0; it < 8; ++it) {
        int cc = cl + it * 16;
        int c = c0 + cc;
        float4 wv = make_float4(0.f, 0.f, 0.f, 0.f);
        if (c < EIDN) wv = *(const float4*)(Weid + (size_t)c * HIDN + k0 + k4 * 4);
        sw[k4 * 4 + 0][cc] = wv.x; sw[k4 * 4 + 1][cc] = wv.y;
        sw[k4 * 4 + 2][cc] = wv.z; sw[k4 * 4 + 3][cc] = wv.w;
      }
    }
    __syncthreads();
#pragma unroll 4
    for (int kk = 0; kk < 64; ++kk) {
      float4 av = *(const float4*)&sh[kk][4 * tr];
      float bw[8];
#pragma unroll
      for (int m = 0; m < 8; ++m) bw[m] = sw[kk][tc + 16 * m];
#pragma unroll
      for (int m = 0; m < 8; ++m) {
        acc[0][m] = fmaf(av.x, bw[m], acc[0][m]);
        acc[1][m] = fmaf(av.y, bw[m], acc[1][m]);
        acc[2][m] = fmaf(av.z, bw[m], acc[2][m]);
        acc[3][m] = fmaf(av.w, bw[m], acc[3][m]);
      }
    }
    __syncthreads();
  }
  // bias, store raw logits, per-row exp-sum + packed argmax
  float sume[4] = {0.f, 0.f, 0.f, 0.f};
  unsigned long long key[4] = {0ULL, 0ULL, 0ULL, 0ULL};
#pragma unroll
  for (int m = 0; m < 8; ++m) {
    int c = c0 + tc + 16 * m;
    if (c < EIDN) {
      float bb = beid[c];
#pragma unroll
      for (int i = 0; i < 4; ++i) {
        float L = acc[i][m] + bb;
        oslice[(size_t)(4 * tr + i) * EIDN + c] = L;
        sume[i] += expf(L);
        unsigned long long pk =
            ((unsigned long long)orderf_(L) << 32) |
            (unsigned long long)(0xFFFFFFFFu - (unsigned)c);   // ties -> smaller c
        if (pk > key[i]) key[i] = pk;
      }
    }
  }
#pragma unroll
  for (int off = 8; off > 0; off >>= 1) {
#pragma unroll
    for (int i = 0; i < 4; ++i) {
      sume[i] += __shfl_down(sume[i], off, 16);
      unsigned long long o = shfl_down_u64(key[i], off, 16);
      if (o > key[i]) key[i] = o;
    }
  }
  if (tc == 0) {
#pragma unroll
    for (int i = 0; i < 4; ++i) {
      int r = 4 * tr + i;
      atomicAdd(&ws->rowsum[r], sume[i]);
      atomicMax(&ws->amax[r], key[i]);
    }
  }
}

// ---------------------------------------------------------------- finalize
// normalize logits in place (log_softmax) + multitask rate head + next-step state
__global__ __launch_bounds__(256) void k_finalize(
    float* __restrict__ oslice, float* __restrict__ rate_out,
    const float* __restrict__ emb_mt, const float* __restrict__ Wr1,
    const float* __restrict__ br1, const float* __restrict__ Wr2,
    const float* __restrict__ br2, const float* __restrict__ h,
    WS* __restrict__ ws) {
  int tid = threadIdx.x;
  __shared__ float logs[BN];
  if (tid < BN) logs[tid] = logf(ws->rowsum[tid]);
  __syncthreads();
  int gid = blockIdx.x * blockDim.x + tid;
  int nt = gridDim.x * blockDim.x;
  const int nf4 = BN * EIDN / 4;     // 480000
  const int rowf4 = EIDN / 4;        // 7500 (row boundary aligns with float4)
  float4* o4 = (float4*)oslice;
  for (int f = gid; f < nf4; f += nt) {
    int b = f / rowf4;
    float lb = logs[b];
    float4 v = o4[f];
    v.x -= lb; v.y -= lb; v.z -= lb; v.w -= lb;
    o4[f] = v;
  }
  if (blockIdx.x < BN) {   // rate head: one WG per batch row
    int b = blockIdx.x;
    int idx = (int)(0xFFFFFFFFu - (unsigned)(ws->amax[b] & 0xFFFFFFFFull));
    __shared__ float cat[EMBN + HIDN];
    cat[tid] = emb_mt[(size_t)idx * EMBN + tid];
    cat[EMBN + tid]       = h[b * HIDN + tid];
    cat[EMBN + 256 + tid] = h[b * HIDN + 256 + tid];
    __syncthreads();
    float part = 0.f;
#pragma unroll
    for (int jj = 0; jj < 2; ++jj) {
      int jdx = tid + jj * 256;
      const float* wr = Wr1 + (size_t)jdx * (EMBN + HIDN);
      float a = br1[jdx];
#pragma unroll 4
      for (int k = 0; k < EMBN + HIDN; ++k) a = fmaf(cat[k], wr[k], a);
      a = fmaxf(a, 0.f);
      part = fmaf(a, Wr2[jdx], part);
    }
#pragma unroll
    for (int off = 32; off > 0; off >>= 1) part += __shfl_down(part, off, 64);
    __shared__ float wsum[4];
    if ((tid & 63) == 0) wsum[tid >> 6] = part;
    __syncthreads();
    if (tid == 0) {
      float tot = wsum[0] + wsum[1] + wsum[2] + wsum[3] + br2[0];
      float rt = sigmoidf_(tot);
      rate_out[b] = rt;
      ws->rate_cur[b] = rt;
      ws->eid_cur[b] = idx;
    }
  }
}

// ---------------------------------------------------------------- zero t=0 slice
__global__ void k_zero_t0(float* __restrict__ out) {
  int gid = blockIdx.x * blockDim.x + threadIdx.x;
  int nt = gridDim.x * blockDim.x;
  float4* o4 = (float4*)out;
  for (int f = gid; f < BN * EIDN / 4; f += nt) o4[f] = make_float4(0.f, 0.f, 0.f, 0.f);
}

// ---------------------------------------------------------------- launcher
extern "C" void kernel_launch(void* const* d_in, const int* in_sizes, int n_in,
                              void* d_out, int out_size, void* d_ws, size_t ws_size,
                              hipStream_t stream) {
  const float* src      = (const float*)d_in[0];
  const int*   src_len  = (const int*)d_in[1];
  const int*   trg_eid  = (const int*)d_in[2];
  const float* trg_rate = (const float*)d_in[3];
  const float* Wih_e    = (const float*)d_in[4];
  const float* Whh_e    = (const float*)d_in[5];
  const float* bih_e    = (const float*)d_in[6];
  const float* bhh_e    = (const float*)d_in[7];
  const float* emb_dec  = (const float*)d_in[8];
  const float* Wih_d    = (const float*)d_in[9];
  const float* Whh_d    = (const float*)d_in[10];
  const float* bih_d    = (const float*)d_in[11];
  const float* bhh_d    = (const float*)d_in[12];
  const float* emb_mt   = (const float*)d_in[13];
  const float* Weid     = (const float*)d_in[14];
  const float* beid     = (const float*)d_in[15];
  const float* Wr1      = (const float*)d_in[16];
  const float* br1      = (const float*)d_in[17];
  const float* Wr2      = (const float*)d_in[18];
  const float* br2      = (const float*)d_in[19];
  float* out = (float*)d_out;

  // scratch: prefer d_ws; fall back to aliasing the t=0 output slice (re-zeroed at end)
  WS* ws = (ws_size >= sizeof(WS)) ? (WS*)d_ws : (WS*)d_out;

  hipLaunchKernelGGL(k_init, dim3(256), dim3(256), 0, stream,
                     Whh_e, trg_eid, trg_rate, out, ws);
  hipLaunchKernelGGL(k_encoder, dim3(BN), dim3(HIDN), 0, stream,
                     src, src_len, Wih_e, bih_e, bhh_e, ws);
  for (int s = 0; s < TRGT - 1; ++s) {
    const float* hin = &ws->hb[s & 1][0][0];
    float* hout = &ws->hb[(s + 1) & 1][0][0];
    hipLaunchKernelGGL(k_dec_gru, dim3(128), dim3(256), 0, stream,
                       emb_dec, Wih_d, Whh_d, bih_d, bhh_d, ws, hin, hout);
    float* oslice = out + (size_t)(s + 1) * BN * EIDN;
    hipLaunchKernelGGL(k_logits, dim3(235), dim3(256), 0, stream,
                       Weid, beid, hout, oslice, ws);
    hipLaunchKernelGGL(k_finalize, dim3(256), dim3(256), 0, stream,
                       oslice, out + (size_t)TRGT * BN * EIDN + (size_t)(s + 1) * BN,
                       emb_mt, Wr1, br1, Wr2, br2, hout, ws);
  }
  hipLaunchKernelGGL(k_zero_t0, dim3(480), dim3(256), 0, stream, out);
}

// Round 2
// 9382.239 us; speedup vs baseline: 1.5761x; 1.5761x over previous
//
#include <hip/hip_runtime.h>
#include <cmath>

#define EIDN  30000
#define EMBN  256
#define HIDN  512
#define INDIM 3
#define SRCT  128
#define TRGT  50
#define BN    64
#define G3H   1536
#define WIH_PAD 260   // padded row length for W_ih_dec (257 -> 260, 16B-aligned rows)

struct alignas(16) WS {
  float wihd[G3H * WIH_PAD];        // padded W_ih_dec
  float hb[2][BN][HIDN];            // ping-pong hidden state
  float rowsum[BN];
  float rate_cur[BN];
  int   eid_cur[BN];
  unsigned long long amax[BN];
};

__device__ __forceinline__ float sigmoidf_(float x) { return 1.f / (1.f + expf(-x)); }

__device__ __forceinline__ unsigned int orderf_(float f) {
  unsigned int b = __float_as_uint(f);
  return b ^ ((b & 0x80000000u) ? 0xFFFFFFFFu : 0x80000000u);
}

__device__ __forceinline__ unsigned long long shfl_down_u64(unsigned long long v, int off, int w) {
  unsigned int lo = (unsigned int)v;
  unsigned int hi = (unsigned int)(v >> 32);
  lo = __shfl_down(lo, off, w);
  hi = __shfl_down(hi, off, w);
  return ((unsigned long long)hi << 32) | (unsigned long long)lo;
}

// 6 parallel dot-products (float4): acc[i] += dot(x[0..4n4), w[i][0..4n4))
__device__ __forceinline__ void dot6(const float* __restrict__ x,
                                     const float* const* __restrict__ w,
                                     int n4, float* __restrict__ acc) {
  const float4* x4 = (const float4*)x;
#pragma unroll 4
  for (int k = 0; k < n4; ++k) {
    float4 xv = x4[k];
#pragma unroll
    for (int i = 0; i < 6; ++i) {
      float4 wv = ((const float4*)w[i])[k];
      acc[i] = fmaf(xv.w, wv.w, fmaf(xv.z, wv.z, fmaf(xv.y, wv.y, fmaf(xv.x, wv.x, acc[i]))));
    }
  }
}

// ---------------------------------------------------------------- init/prep
__global__ void k_init(const float* __restrict__ Wih_d,
                       const int* __restrict__ trg_eid,
                       const float* __restrict__ trg_rate,
                       float* __restrict__ out, WS* __restrict__ ws) {
  int gid = blockIdx.x * blockDim.x + threadIdx.x;
  int nt = gridDim.x * blockDim.x;
  // pad-copy W_ih_dec [1536][257] -> [1536][260]
  const int N = G3H * 257;
  for (int i = gid; i < N; i += nt) {
    int r = i / 257, c = i - r * 257;
    ws->wihd[r * WIH_PAD + c] = Wih_d[i];
  }
  float* hb0 = &ws->hb[0][0][0];
  for (int i = gid; i < BN * HIDN; i += nt) hb0[i] = 0.f;
  if (gid < BN) {
    ws->eid_cur[gid]  = trg_eid[gid];
    ws->rate_cur[gid] = trg_rate[gid];
    out[(size_t)TRGT * BN * EIDN + gid] = 0.f;  // rate_result row 0
  }
}

// ---------------------------------------------------------------- encoder step
// grid 256: WG owns 2 hidden units (6 W_hh rows). thread = (b, k-quarter).
__global__ __launch_bounds__(256) void k_enc_step(
    const float* __restrict__ src, const int* __restrict__ src_len,
    const float* __restrict__ Wih, const float* __restrict__ bih,
    const float* __restrict__ bhh, const float* __restrict__ Whh,
    const float* __restrict__ hin, float* __restrict__ hout, int t) {
  __shared__ float part[BN][4][6];
  int tid = threadIdx.x;
  int b = tid & 63, kq = tid >> 6;
  int j0 = blockIdx.x * 2;

  const float* wrows[6];
#pragma unroll
  for (int idx = 0; idx < 6; ++idx) {
    int u = idx / 3, g = idx - 3 * u;
    wrows[idx] = Whh + (size_t)(g * HIDN + j0 + u) * HIDN + kq * 128;
  }
  float acc[6] = {0.f, 0.f, 0.f, 0.f, 0.f, 0.f};
  dot6(hin + b * HIDN + kq * 128, wrows, 32, acc);
#pragma unroll
  for (int idx = 0; idx < 6; ++idx) part[b][kq][idx] = acc[idx];
  __syncthreads();

  if (kq == 0) {
    int len = src_len[b];
    const float* x = src + ((size_t)t * BN + b) * INDIM;
    float x0 = x[0], x1 = x[1], x2 = x[2];
#pragma unroll
    for (int u = 0; u < 2; ++u) {
      int j = j0 + u;
      float hg[3], ig[3];
#pragma unroll
      for (int g = 0; g < 3; ++g) {
        int idx = u * 3 + g;
        hg[g] = part[b][0][idx] + part[b][1][idx] + part[b][2][idx] + part[b][3][idx]
                + bhh[g * HIDN + j];
        int row = g * HIDN + j;
        ig[g] = bih[row] + x0 * Wih[row * 3] + x1 * Wih[row * 3 + 1] + x2 * Wih[row * 3 + 2];
      }
      float r = sigmoidf_(ig[0] + hg[0]);
      float z = sigmoidf_(ig[1] + hg[1]);
      float n = tanhf(ig[2] + r * hg[2]);
      float ho = hin[b * HIDN + j];
      hout[b * HIDN + j] = (t < len) ? ((1.f - z) * n + z * ho) : ho;
    }
  }
}

// ---------------------------------------------------------------- decoder GRU cell
// grid 256: WG owns 2 hidden units. K=769 split in 4 balanced slices across kq.
__global__ __launch_bounds__(256) void k_dec_gru(
    const float* __restrict__ emb_dec, const float* __restrict__ Whh,
    const float* __restrict__ bih, const float* __restrict__ bhh,
    WS* __restrict__ ws, const float* __restrict__ hin, float* __restrict__ hout) {
  __shared__ float partx[BN][4][6];
  __shared__ float parth[BN][4][6];
  int tid = threadIdx.x;
  if (blockIdx.x == 0 && tid < BN) {   // reset reductions for upcoming k_logits
    ws->rowsum[tid] = 0.f;
    ws->amax[tid] = 0ULL;
  }
  int b = tid & 63, kq = tid >> 6;
  int j0 = blockIdx.x * 2;
  int eid = ws->eid_cur[b];
  const float* xe = emb_dec + (size_t)eid * EMBN;
  const float* hrow = hin + b * HIDN;

  float accx[6] = {0.f, 0.f, 0.f, 0.f, 0.f, 0.f};
  float acch[6] = {0.f, 0.f, 0.f, 0.f, 0.f, 0.f};
  const float* w[6];

  if (kq == 0) {            // emb[0,192)
#pragma unroll
    for (int idx = 0; idx < 6; ++idx) {
      int u = idx / 3, g = idx - 3 * u;
      w[idx] = ws->wihd + (size_t)(g * HIDN + j0 + u) * WIH_PAD;
    }
    dot6(xe, w, 48, accx);
  } else if (kq == 1) {     // emb[192,256) + rate + h[0,128)
    float rate = ws->rate_cur[b];
#pragma unroll
    for (int idx = 0; idx < 6; ++idx) {
      int u = idx / 3, g = idx - 3 * u;
      const float* wr = ws->wihd + (size_t)(g * HIDN + j0 + u) * WIH_PAD;
      w[idx] = wr + 192;
      accx[idx] = rate * wr[256];
    }
    dot6(xe + 192, w, 16, accx);
#pragma unroll
    for (int idx = 0; idx < 6; ++idx) {
      int u = idx / 3, g = idx - 3 * u;
      w[idx] = Whh + (size_t)(g * HIDN + j0 + u) * HIDN;
    }
    dot6(hrow, w, 32, acch);
  } else {                  // kq=2: h[128,320), kq=3: h[320,512)
    int off = (kq == 2) ? 128 : 320;
#pragma unroll
    for (int idx = 0; idx < 6; ++idx) {
      int u = idx / 3, g = idx - 3 * u;
      w[idx] = Whh + (size_t)(g * HIDN + j0 + u) * HIDN + off;
    }
    dot6(hrow + off, w, 48, acch);
  }
#pragma unroll
  for (int idx = 0; idx < 6; ++idx) {
    partx[b][kq][idx] = accx[idx];
    parth[b][kq][idx] = acch[idx];
  }
  __syncthreads();

  if (kq == 0) {
#pragma unroll
    for (int u = 0; u < 2; ++u) {
      int j = j0 + u;
      float ix[3], hh[3];
#pragma unroll
      for (int g = 0; g < 3; ++g) {
        int idx = u * 3 + g;
        ix[g] = partx[b][0][idx] + partx[b][1][idx] + partx[b][2][idx] + partx[b][3][idx]
                + bih[g * HIDN + j];
        hh[g] = parth[b][0][idx] + parth[b][1][idx] + parth[b][2][idx] + parth[b][3][idx]
                + bhh[g * HIDN + j];
      }
      float r = sigmoidf_(ix[0] + hh[0]);
      float z = sigmoidf_(ix[1] + hh[1]);
      float n = tanhf(ix[2] + r * hh[2]);
      hout[b * HIDN + j] = (1.f - z) * n + z * hin[b * HIDN + j];
    }
  }
}

// ---------------------------------------------------------------- big GEMM + reductions
// grid 469: WG = 64 cols x 64 rows, fp32 LDS-tiled, float4 both operands.
__global__ __launch_bounds__(256) void k_logits(
    const float* __restrict__ Weid, const float* __restrict__ beid,
    const float* __restrict__ h, float* __restrict__ oslice,
    WS* __restrict__ ws) {
  __shared__ float sh[64][68];   // [k][r]
  __shared__ float sw[64][68];   // [k][c]
  int tid = threadIdx.x;
  int tr = tid >> 4, tc = tid & 15;
  int c0 = blockIdx.x * 64;
  float acc[4][4];
#pragma unroll
  for (int i = 0; i < 4; ++i)
#pragma unroll
    for (int m = 0; m < 4; ++m) acc[i][m] = 0.f;

  for (int kc = 0; kc < 8; ++kc) {
    int k0 = kc * 64;
#pragma unroll
    for (int u = 0; u < 4; ++u) {
      int flat = tid + u * 256;
      int r = flat >> 4, k4 = flat & 15;
      float4 hv = *(const float4*)(h + r * HIDN + k0 + k4 * 4);
      sh[k4 * 4 + 0][r] = hv.x; sh[k4 * 4 + 1][r] = hv.y;
      sh[k4 * 4 + 2][r] = hv.z; sh[k4 * 4 + 3][r] = hv.w;
      int c = c0 + r;
      float4 wv = make_float4(0.f, 0.f, 0.f, 0.f);
      if (c < EIDN) wv = *(const float4*)(Weid + (size_t)c * HIDN + k0 + k4 * 4);
      sw[k4 * 4 + 0][r] = wv.x; sw[k4 * 4 + 1][r] = wv.y;
      sw[k4 * 4 + 2][r] = wv.z; sw[k4 * 4 + 3][r] = wv.w;
    }
    __syncthreads();
#pragma unroll 8
    for (int kk = 0; kk < 64; ++kk) {
      float4 av = *(const float4*)&sh[kk][4 * tr];
      float4 bv = *(const float4*)&sw[kk][4 * tc];
      acc[0][0] = fmaf(av.x, bv.x, acc[0][0]); acc[0][1] = fmaf(av.x, bv.y, acc[0][1]);
      acc[0][2] = fmaf(av.x, bv.z, acc[0][2]); acc[0][3] = fmaf(av.x, bv.w, acc[0][3]);
      acc[1][0] = fmaf(av.y, bv.x, acc[1][0]); acc[1][1] = fmaf(av.y, bv.y, acc[1][1]);
      acc[1][2] = fmaf(av.y, bv.z, acc[1][2]); acc[1][3] = fmaf(av.y, bv.w, acc[1][3]);
      acc[2][0] = fmaf(av.z, bv.x, acc[2][0]); acc[2][1] = fmaf(av.z, bv.y, acc[2][1]);
      acc[2][2] = fmaf(av.z, bv.z, acc[2][2]); acc[2][3] = fmaf(av.z, bv.w, acc[2][3]);
      acc[3][0] = fmaf(av.w, bv.x, acc[3][0]); acc[3][1] = fmaf(av.w, bv.y, acc[3][1]);
      acc[3][2] = fmaf(av.w, bv.z, acc[3][2]); acc[3][3] = fmaf(av.w, bv.w, acc[3][3]);
    }
    __syncthreads();
  }

  int cbase = c0 + 4 * tc;
  float sume[4] = {0.f, 0.f, 0.f, 0.f};
  unsigned long long key[4] = {0ULL, 0ULL, 0ULL, 0ULL};
  if (cbase + 3 < EIDN) {
    float4 bb = *(const float4*)(beid + cbase);
#pragma unroll
    for (int i = 0; i < 4; ++i) {
      float4 L;
      L.x = acc[i][0] + bb.x; L.y = acc[i][1] + bb.y;
      L.z = acc[i][2] + bb.z; L.w = acc[i][3] + bb.w;
      *(float4*)(oslice + (size_t)(4 * tr + i) * EIDN + cbase) = L;
      sume[i] = expf(L.x) + expf(L.y) + expf(L.z) + expf(L.w);
      float lv[4] = {L.x, L.y, L.z, L.w};
#pragma unroll
      for (int cc = 0; cc < 4; ++cc) {
        unsigned long long pk = ((unsigned long long)orderf_(lv[cc]) << 32) |
                                (unsigned long long)(0xFFFFFFFFu - (unsigned)(cbase + cc));
        if (pk > key[i]) key[i] = pk;
      }
    }
  }
#pragma unroll
  for (int off = 8; off > 0; off >>= 1) {
#pragma unroll
    for (int i = 0; i < 4; ++i) {
      sume[i] += __shfl_down(sume[i], off, 16);
      unsigned long long o = shfl_down_u64(key[i], off, 16);
      if (o > key[i]) key[i] = o;
    }
  }
  if (tc == 0) {
#pragma unroll
    for (int i = 0; i < 4; ++i) {
      int r = 4 * tr + i;
      atomicAdd(&ws->rowsum[r], sume[i]);
      atomicMax(&ws->amax[r], key[i]);
    }
  }
}

// ---------------------------------------------------------------- finalize
__global__ __launch_bounds__(256) void k_finalize(
    float* __restrict__ oslice, float* __restrict__ rate_out,
    const float* __restrict__ emb_mt, const float* __restrict__ Wr1,
    const float* __restrict__ br1, const float* __restrict__ Wr2,
    const float* __restrict__ br2, const float* __restrict__ h,
    WS* __restrict__ ws) {
  int tid = threadIdx.x;
  __shared__ float logs[BN];
  if (tid < BN) logs[tid] = logf(ws->rowsum[tid]);
  __syncthreads();
  int gid = blockIdx.x * blockDim.x + tid;
  int nt = gridDim.x * blockDim.x;
  const int nf4 = BN * EIDN / 4;
  const int rowf4 = EIDN / 4;
  float4* o4 = (float4*)oslice;
  for (int f = gid; f < nf4; f += nt) {
    int b = f / rowf4;
    float lb = logs[b];
    float4 v = o4[f];
    v.x -= lb; v.y -= lb; v.z -= lb; v.w -= lb;
    o4[f] = v;
  }
  if (blockIdx.x < BN) {   // rate head: one WG per batch row
    int b = blockIdx.x;
    int idx = (int)(0xFFFFFFFFu - (unsigned)(ws->amax[b] & 0xFFFFFFFFull));
    __shared__ float cat[EMBN + HIDN];
    cat[tid]       = emb_mt[(size_t)idx * EMBN + tid];
    cat[EMBN + tid]       = h[b * HIDN + tid];
    cat[EMBN + 256 + tid] = h[b * HIDN + 256 + tid];
    __syncthreads();
    const float4* c4 = (const float4*)cat;
    int j0 = tid * 2;
    const float4* w0 = (const float4*)(Wr1 + (size_t)j0 * (EMBN + HIDN));
    const float4* w1 = (const float4*)(Wr1 + (size_t)(j0 + 1) * (EMBN + HIDN));
    float a0 = br1[j0], a1 = br1[j0 + 1];
#pragma unroll 4
    for (int k = 0; k < (EMBN + HIDN) / 4; ++k) {
      float4 cv = c4[k];
      float4 v0 = w0[k], v1 = w1[k];
      a0 = fmaf(cv.w, v0.w, fmaf(cv.z, v0.z, fmaf(cv.y, v0.y, fmaf(cv.x, v0.x, a0))));
      a1 = fmaf(cv.w, v1.w, fmaf(cv.z, v1.z, fmaf(cv.y, v1.y, fmaf(cv.x, v1.x, a1))));
    }
    float part = fmaxf(a0, 0.f) * Wr2[j0] + fmaxf(a1, 0.f) * Wr2[j0 + 1];
#pragma unroll
    for (int off = 32; off > 0; off >>= 1) part += __shfl_down(part, off, 64);
    __shared__ float wsum[4];
    if ((tid & 63) == 0) wsum[tid >> 6] = part;
    __syncthreads();
    if (tid == 0) {
      float tot = wsum[0] + wsum[1] + wsum[2] + wsum[3] + br2[0];
      float rt = sigmoidf_(tot);
      rate_out[b] = rt;
      ws->rate_cur[b] = rt;
      ws->eid_cur[b] = idx;
    }
  }
}

// ---------------------------------------------------------------- zero t=0 slice
__global__ void k_zero_t0(float* __restrict__ out) {
  int gid = blockIdx.x * blockDim.x + threadIdx.x;
  int nt = gridDim.x * blockDim.x;
  float4* o4 = (float4*)out;
  for (int f = gid; f < BN * EIDN / 4; f += nt) o4[f] = make_float4(0.f, 0.f, 0.f, 0.f);
}

// ---------------------------------------------------------------- launcher
extern "C" void kernel_launch(void* const* d_in, const int* in_sizes, int n_in,
                              void* d_out, int out_size, void* d_ws, size_t ws_size,
                              hipStream_t stream) {
  const float* src      = (const float*)d_in[0];
  const int*   src_len  = (const int*)d_in[1];
  const int*   trg_eid  = (const int*)d_in[2];
  const float* trg_rate = (const float*)d_in[3];
  const float* Wih_e    = (const float*)d_in[4];
  const float* Whh_e    = (const float*)d_in[5];
  const float* bih_e    = (const float*)d_in[6];
  const float* bhh_e    = (const float*)d_in[7];
  const float* emb_dec  = (const float*)d_in[8];
  const float* Wih_d    = (const float*)d_in[9];
  const float* Whh_d    = (const float*)d_in[10];
  const float* bih_d    = (const float*)d_in[11];
  const float* bhh_d    = (const float*)d_in[12];
  const float* emb_mt   = (const float*)d_in[13];
  const float* Weid     = (const float*)d_in[14];
  const float* beid     = (const float*)d_in[15];
  const float* Wr1      = (const float*)d_in[16];
  const float* br1      = (const float*)d_in[17];
  const float* Wr2      = (const float*)d_in[18];
  const float* br2      = (const float*)d_in[19];
  float* out = (float*)d_out;

  WS* ws = (ws_size >= sizeof(WS)) ? (WS*)d_ws : (WS*)d_out;

  hipLaunchKernelGGL(k_init, dim3(256), dim3(256), 0, stream,
                     Wih_d, trg_eid, trg_rate, out, ws);
  for (int t = 0; t < SRCT; ++t) {
    const float* hin = &ws->hb[t & 1][0][0];
    float* hout = &ws->hb[(t + 1) & 1][0][0];
    hipLaunchKernelGGL(k_enc_step, dim3(256), dim3(256), 0, stream,
                       src, src_len, Wih_e, bih_e, bhh_e, Whh_e, hin, hout, t);
  }
  // after t=127, final hidden is in hb[0]
  for (int s = 0; s < TRGT - 1; ++s) {
    const float* hin = &ws->hb[s & 1][0][0];
    float* hout = &ws->hb[(s + 1) & 1][0][0];
    hipLaunchKernelGGL(k_dec_gru, dim3(256), dim3(256), 0, stream,
                       emb_dec, Whh_d, bih_d, bhh_d, ws, hin, hout);
    float* oslice = out + (size_t)(s + 1) * BN * EIDN;
    hipLaunchKernelGGL(k_logits, dim3((EIDN + 63) / 64), dim3(256), 0, stream,
                       Weid, beid, hout, oslice, ws);
    hipLaunchKernelGGL(k_finalize, dim3(512), dim3(256), 0, stream,
                       oslice, out + (size_t)TRGT * BN * EIDN + (size_t)(s + 1) * BN,
                       emb_mt, Wr1, br1, Wr2, br2, hout, ws);
  }
  hipLaunchKernelGGL(k_zero_t0, dim3(480), dim3(256), 0, stream, out);
}